// Round 18
// baseline (801.446 us; speedup 1.0000x reference)
//
#include <hip/hip_runtime.h>

// ---------------- constants ----------------
constexpr int kE   = 2048;
constexpr int kS   = 32;
constexpr int kD   = 256;
constexpr int kK   = 512;
constexpr int kREL = 500;
constexpr int kN   = 1024;

typedef unsigned short u16;
typedef __attribute__((ext_vector_type(8))) _Float16 f16x8;
typedef __attribute__((ext_vector_type(4))) float    f32x4;
typedef __attribute__((ext_vector_type(4))) unsigned short us4;

static __device__ __forceinline__ u16 f2h(float f) {
  _Float16 h = (_Float16)f;
  return __builtin_bit_cast(u16, h);
}
static __device__ __forceinline__ float h2f(u16 v) {
  _Float16 h = __builtin_bit_cast(_Float16, v);
  return (float)h;
}
static __device__ __forceinline__ float sigf(float x) { return 1.f / (1.f + __expf(-x)); }
static __device__ __forceinline__ float tanhfast(float x) {
  float e = __expf(2.f * x);
  return 1.f - 2.f / (e + 1.f);
}
static __device__ __forceinline__ void gl_lds16(const void* g, void* l) {
  __builtin_amdgcn_global_load_lds((const __attribute__((address_space(1))) unsigned int*)g,
                                   (__attribute__((address_space(3))) unsigned int*)l, 16, 0, 0);
}

// ---------------- prep+gather fused ----------------
__global__ void prep_gather(const float* __restrict__ Wih_f, const float* __restrict__ Whh_f,
                            const float* __restrict__ Wih_b, const float* __restrict__ Whh_b,
                            const float* __restrict__ Wlin_in,
                            const int* __restrict__ neighbors, const float* __restrict__ ent,
                            u16* __restrict__ Wv3, u16* __restrict__ Whhr,
                            u16* __restrict__ Wlin, u16* __restrict__ ximg) {
  if (blockIdx.x < 576) {
    int idx = blockIdx.x * 256 + threadIdx.x;
    if (idx < 65536) {                       // Wv3: 2d x 4y x 4ch x 2048 units
      int q  = idx & 2047;
      int ch = (idx >> 11) & 3;
      int y  = (idx >> 13) & 3;
      int d  = idx >> 15;
      int j  = q >> 3;
      int k8 = (q & 7) ^ (j & 7);
      int jg = y * 256 + j;
      int g = (jg >> 4) & 3, u = (jg >> 6) * 16 + (jg & 15);
      int R = g * 256 + u;
      int k = ch * 64 + k8 * 8;
      const float* src = (d ? Wih_b : Wih_f) + R * 256 + k;
      ushort oa[8];
#pragma unroll
      for (int i = 0; i < 8; i++) oa[i] = f2h(src[i]);
      *(uint4*)((char*)Wv3 + (size_t)idx * 16) = *(uint4*)oa;
    } else if (idx < 131072) {               // Whhr row-major
      int i2 = idx - 65536;
      int d = i2 >> 15;
      int j = (i2 & 32767) >> 5;
      int k = (i2 & 31) * 8;
      int g = (j >> 4) & 3, u = (j >> 6) * 16 + (j & 15);
      int R = g * 256 + u;
      const float* src = (d ? Whh_b : Whh_f) + R * 256 + k;
      ushort oa[8];
#pragma unroll
      for (int i = 0; i < 8; i++) oa[i] = f2h(src[i]);
      *(uint4*)((char*)Whhr + (size_t)i2 * 16) = *(uint4*)oa;
    } else if (idx < 131072 + 16384) {       // Wlin
      int q = (idx - 131072) * 8;
#pragma unroll
      for (int i = 0; i < 8; i++) Wlin[q + i] = f2h(Wlin_in[q + i]);
    }
  } else {
    int idx = (blockIdx.x - 576) * 256 + threadIdx.x;   // ximg units
    int q    = idx & 511;
    int ch   = (idx >> 9) & 3;
    int tile = (idx >> 11) & 31;
    int s    = idx >> 16;
    int row = q >> 3;
    int c8 = (q & 7) ^ (row & 7);
    int e = tile * 64 + row;
    int k = ch * 64 + c8 * 8;
    int nb = neighbors[e * 32 + s];
    const float* src = ent + (size_t)nb * 256 + k;
    float4 v0 = *(const float4*)src;
    float4 v1 = *(const float4*)(src + 4);
    ushort oa[8];
    oa[0] = f2h(v0.x); oa[1] = f2h(v0.y); oa[2] = f2h(v0.z); oa[3] = f2h(v0.w);
    oa[4] = f2h(v1.x); oa[5] = f2h(v1.y); oa[6] = f2h(v1.z); oa[7] = f2h(v1.w);
    *(uint4*)((char*)ximg + (size_t)idx * 16) = *(uint4*)oa;
  }
}

// ---------------- bulk xgemm: all 32 steps, LDS via gl_lds, bias in C-init ----------------
__global__ __launch_bounds__(256) void xgemm(
    const u16* __restrict__ ximg, const u16* __restrict__ Wv3,
    const float* __restrict__ b_f, const float* __restrict__ b_b,
    u16* __restrict__ gx) {
  __shared__ __align__(16) char As[8192];
  __shared__ __align__(16) char Bs[32768];
  const int tid = threadIdx.x, lane = tid & 63, w = tid >> 6;
  const int l15 = lane & 15, lq = lane >> 4;
  const int ts = blockIdx.x >> 5;
  const int etile = blockIdx.x & 31;
  const int y = blockIdx.y, dir = blockIdx.z;
  const int e0 = etile * 64;
  const int s = dir ? (31 - ts) : ts;
  const char* imgA = (const char*)ximg + (size_t)(s * 32 + etile) * 32768;
  const char* imgB = (const char*)Wv3 + (size_t)(dir * 4 + y) * 131072;
  const float* bd = dir ? b_b : b_f;
  const int u = (y * 4 + w) * 16 + l15;

  f32x4 acc[4][4];
#pragma unroll
  for (int n = 0; n < 4; n++) {
    float bv = bd[n * 256 + u];
#pragma unroll
    for (int m = 0; m < 4; m++) acc[m][n] = (f32x4){bv, bv, bv, bv};
  }

  for (int ch = 0; ch < 4; ++ch) {
#pragma unroll
    for (int i = 0; i < 2; i++)
      gl_lds16(imgA + ch * 8192 + i * 4096 + w * 1024 + lane * 16,
               As + i * 4096 + w * 1024);
#pragma unroll
    for (int i = 0; i < 8; i++)
      gl_lds16(imgB + (size_t)ch * 32768 + i * 4096 + w * 1024 + lane * 16,
               Bs + i * 4096 + w * 1024);
    __syncthreads();
#pragma unroll
    for (int ks = 0; ks < 2; ++ks) {
      const int kb = ks * 64 + lq * 16;
      f16x8 a[4], b[4];
#pragma unroll
      for (int m = 0; m < 4; m++) {
        int row = m * 16 + l15;
        a[m] = *(const f16x8*)(As + row * 128 + (kb ^ ((row & 7) << 4)));
      }
#pragma unroll
      for (int n = 0; n < 4; n++) {
        int row = w * 64 + n * 16 + l15;
        b[n] = *(const f16x8*)(Bs + row * 128 + (kb ^ ((row & 7) << 4)));
      }
#pragma unroll
      for (int m = 0; m < 4; m++)
#pragma unroll
        for (int n = 0; n < 4; n++)
          acc[m][n] = __builtin_amdgcn_mfma_f32_16x16x32_f16(a[m], b[n], acc[m][n], 0, 0, 0);
    }
    __syncthreads();
  }

  u16* out = gx + ((size_t)(dir * kS + ts) * kE) * 1024;
#pragma unroll
  for (int m = 0; m < 4; m++)
#pragma unroll
    for (int r = 0; r < 4; r++) {
      int e = e0 + m * 16 + lq * 4 + r;
      us4 o;
      o[0] = f2h(acc[m][0][r]); o[1] = f2h(acc[m][1][r]);
      o[2] = f2h(acc[m][2][r]); o[3] = f2h(acc[m][3][r]);
      __builtin_nontemporal_store(o, (us4*)(out + ((size_t)e * 256 + u) * 4));
    }
}

// ---------------- one LSTM step, h-half (K=256), 256 blocks, wave 64e x 64j ----------------
__global__ __launch_bounds__(256) void lstm_step(
    const u16* __restrict__ gx, const u16* __restrict__ Whhr,
    const u16* __restrict__ hprev, u16* __restrict__ hnext,
    float* __restrict__ cbuf, int t) {
  const int tid = threadIdx.x, lane = tid & 63, w = tid >> 6;
  const int l15 = lane & 15, lq = lane >> 4;
  const int bid = blockIdx.x;
  const int dir = bid >> 7;
  const int ut  = (bid >> 4) & 7;
  const int et  = bid & 15;
  const int wr = w >> 1, wc = w & 1;
  const int e0 = et * 128 + wr * 64;
  const int c0 = ut * 128 + wc * 64;
  const int unit = (c0 >> 6) * 16 + l15;

  const u16* Wd  = Whhr + (size_t)dir * 1024 * kD;
  const u16* hpd = hprev + (size_t)dir * kE * kD;
  u16* hnd = hnext + (size_t)dir * kE * kD;
  float* cd = cbuf + (size_t)dir * kE * kD;
  const u16* gp = gx + ((size_t)(dir * kS + t) * kE) * 1024;

  f32x4 acc[4][4];
#pragma unroll
  for (int m = 0; m < 4; m++)
#pragma unroll
    for (int r = 0; r < 4; r++) {
      us4 g = __builtin_nontemporal_load(
          (const us4*)(gp + (size_t)(e0 + m * 16 + lq * 4 + r) * 1024 + unit * 4));
#pragma unroll
      for (int n = 0; n < 4; n++) acc[m][n][r] = h2f(g[n]);
    }

  const int klane = lq * 8;
#pragma unroll
  for (int ks = 0; ks < 8; ks++) {
    const int ka = ks * 32 + klane;
    f16x8 a[4], b[4];
#pragma unroll
    for (int m = 0; m < 4; m++)
      a[m] = *(const f16x8*)(hpd + (size_t)(e0 + m * 16 + l15) * kD + ka);
#pragma unroll
    for (int n = 0; n < 4; n++)
      b[n] = *(const f16x8*)(Wd + (size_t)(c0 + n * 16 + l15) * kD + ka);
#pragma unroll
    for (int m = 0; m < 4; m++)
#pragma unroll
      for (int n = 0; n < 4; n++)
        acc[m][n] = __builtin_amdgcn_mfma_f32_16x16x32_f16(a[m], b[n], acc[m][n], 0, 0, 0);
  }

#pragma unroll
  for (int m = 0; m < 4; m++)
#pragma unroll
    for (int r = 0; r < 4; r++) {
      int row = e0 + m * 16 + lq * 4 + r;
      size_t off = (size_t)row * kD + unit;
      float gi = acc[m][0][r];
      float gf = acc[m][1][r];
      float gg = acc[m][2][r];
      float go = acc[m][3][r];
      float c_old = cd[off];
      float cn = sigf(gf) * c_old + sigf(gi) * tanhfast(gg);
      cd[off] = cn;
      hnd[off] = f2h(sigf(go) * tanhfast(cn));
    }
}

// ---------------- shared MFMA GEMM tile (used by lin) ----------------
static __device__ __forceinline__ void gemm_tile(
    const u16* __restrict__ Alo, const u16* __restrict__ Ahi,
    const u16* __restrict__ W, int e0,
    u16* As, u16* Bs, f32x4 (&acc)[4][4]) {
  const int tid = threadIdx.x;
  const int lane = tid & 63;
  const int w = tid >> 6;
#pragma unroll
  for (int m = 0; m < 4; m++)
#pragma unroll
    for (int n = 0; n < 4; n++) acc[m][n] = (f32x4){0.f, 0.f, 0.f, 0.f};

  for (int ch = 0; ch < 8; ++ch) {
    const int k0 = ch * 64;
    __syncthreads();
    const u16* Asrc = (k0 < 256) ? Alo : Ahi;
    const int kbase = (k0 < 256) ? k0 : (k0 - 256);
#pragma unroll
    for (int i = 0; i < 2; i++) {
      int idx = tid + i * 256;
      int row = idx >> 3, c8 = idx & 7;
      uint4 v = *(const uint4*)(Asrc + (size_t)(e0 + row) * 256 + kbase + c8 * 8);
      *(uint4*)((char*)As + row * 128 + ((c8 * 16) ^ ((row & 7) << 4))) = v;
    }
#pragma unroll
    for (int i = 0; i < 8; i++) {
      int idx = tid + i * 256;
      int j = idx >> 3, c8 = idx & 7;
      uint4 v = *(const uint4*)(W + (size_t)j * kK + k0 + c8 * 8);
      *(uint4*)((char*)Bs + j * 128 + ((c8 * 16) ^ ((j & 7) << 4))) = v;
    }
    __syncthreads();
#pragma unroll
    for (int ks = 0; ks < 2; ++ks) {
      const int kb = ks * 64 + (lane >> 4) * 16;
      f16x8 a[4], b[4];
#pragma unroll
      for (int m = 0; m < 4; m++) {
        int row = m * 16 + (lane & 15);
        a[m] = *(const f16x8*)((const char*)As + row * 128 + (kb ^ ((row & 7) << 4)));
      }
#pragma unroll
      for (int n = 0; n < 4; n++) {
        int row = w * 64 + n * 16 + (lane & 15);
        b[n] = *(const f16x8*)((const char*)Bs + row * 128 + (kb ^ ((row & 7) << 4)));
      }
#pragma unroll
      for (int m = 0; m < 4; m++)
#pragma unroll
        for (int n = 0; n < 4; n++)
          acc[m][n] = __builtin_amdgcn_mfma_f32_16x16x32_f16(a[m], b[n], acc[m][n], 0, 0, 0);
    }
  }
}

// ---------------- lin + fused BN partials ----------------
__global__ __launch_bounds__(256) void lin_kernel(
    const u16* __restrict__ hf, const u16* __restrict__ hb,
    const u16* __restrict__ Wl, const float* __restrict__ b_lin,
    float* __restrict__ lin, float* __restrict__ part) {
  __shared__ __align__(16) char smem[40960];
  u16* As = (u16*)smem;
  u16* Bs = (u16*)(smem + 8192);
  const int tid = threadIdx.x, lane = tid & 63, w = tid >> 6;
  const int l15 = lane & 15, lq = lane >> 4;
  const int e0 = blockIdx.x * 64;
  f32x4 acc[4][4];
  gemm_tile(hf, hb, Wl, e0, As, Bs, acc);
#pragma unroll
  for (int n = 0; n < 4; n++) {
    int col = w * 64 + n * 16 + l15;
    float bl = b_lin[col];
    float s1 = 0.f, s2 = 0.f;
#pragma unroll
    for (int m = 0; m < 4; m++)
#pragma unroll
      for (int r = 0; r < 4; r++) {
        int e = e0 + m * 16 + lq * 4 + r;
        float v = acc[m][n][r] + bl;
        lin[(size_t)e * 256 + col] = v;
        s1 += v; s2 += v * v;
      }
    s1 += __shfl_down(s1, 16); s2 += __shfl_down(s2, 16);
    s1 += __shfl_down(s1, 32); s2 += __shfl_down(s2, 32);
    if (lq == 0) {
      part[blockIdx.x * 256 + col] = s1;
      part[8192 + blockIdx.x * 256 + col] = s2;
    }
  }
}

// ---------------- BN finalize + tanh ----------------
__global__ void bn_apply(const float* __restrict__ lin, const float* __restrict__ part,
                         const float* __restrict__ gamma, const float* __restrict__ beta,
                         float* __restrict__ ctx) {
  int c = threadIdx.x;
  float s = 0.f, s2 = 0.f;
  for (int b = 0; b < 32; b++) { s += part[b * 256 + c]; s2 += part[8192 + b * 256 + c]; }
  float mu = s * (1.f / 2048.f);
  float rsig = rsqrtf(s2 * (1.f / 2048.f) - mu * mu + 1e-5f);
  float ga = gamma[c], be = beta[c];
  int e0 = blockIdx.x * 8;
  for (int e = e0; e < e0 + 8; ++e) {
    float x = lin[(size_t)e * 256 + c];
    ctx[(size_t)e * 256 + c] = tanhf(ga * (x - mu) * rsig + be);
  }
}

// ---------------- relation grouping ----------------
__global__ void group_rel(const int* __restrict__ pr, const int* __restrict__ nr,
                          int* __restrict__ offs, int* __restrict__ list) {
  __shared__ int cnt[512], sc[512], cur[512];
  int tid = threadIdx.x;
  cnt[tid] = 0;
  __syncthreads();
  for (int i = tid; i < 2 * kN; i += 512) {
    int r = (i < kN) ? pr[i] : nr[i - kN];
    atomicAdd(&cnt[r], 1);
  }
  __syncthreads();
  sc[tid] = cnt[tid];
  __syncthreads();
  for (int d = 1; d < 512; d <<= 1) {
    int v = (tid >= d) ? sc[tid - d] : 0;
    __syncthreads();
    sc[tid] += v;
    __syncthreads();
  }
  int excl = (tid == 0) ? 0 : sc[tid - 1];
  cur[tid] = excl;
  if (tid <= kREL) offs[tid] = excl;
  __syncthreads();
  for (int i = tid; i < 2 * kN; i += 512) {
    int r = (i < kN) ? pr[i] : nr[i - kN];
    int p = atomicAdd(&cur[r], 1);
    list[p] = i;
  }
}

// ---------------- scores v3b: NJ<=8, 4-float4 W bursts, reg-capped ----------------
template <int NJ>
static __device__ __forceinline__ void score_body(
    const float* __restrict__ ctx, const float* __restrict__ trans,
    const float* __restrict__ rel_embed,
    const int* __restrict__ ph, const int* __restrict__ pt,
    const int* __restrict__ nh, const int* __restrict__ nt,
    const int* __restrict__ list, float* __restrict__ sqacc,
    int r, int half, int start, int G,
    float* csh, float* cst, float (*red)[4], int* tidx) {
  const int tid = threadIdx.x;
#pragma unroll
  for (int j = 0; j < NJ; j++) {
    float vh = 0.f, vt = 0.f;
    if (j < G) {
      int i = list[start + j];
      int hh = (i < kN) ? ph[i] : nh[i - kN];
      int tt = (i < kN) ? pt[i] : nt[i - kN];
      vh = ctx[(size_t)hh * 256 + tid];
      vt = ctx[(size_t)tt * 256 + tid];
      if (tid == 0) tidx[j] = i;
    }
    csh[j * 256 + tid] = vh;
    cst[j * 256 + tid] = vt;
  }
  __syncthreads();

  const int row = half * 128 + (tid >> 1);
  const int q4b = (tid & 1) * 32;
  const float4* whp = (const float4*)(trans + (size_t)r * 65536 + (size_t)row * 256) + q4b;
  const float4* wtp = (const float4*)(trans + ((size_t)r + kREL) * 65536 + (size_t)row * 256) + q4b;
  const float4* ch4 = (const float4*)csh;
  const float4* ct4 = (const float4*)cst;

  float acc[NJ];
#pragma unroll
  for (int j = 0; j < NJ; j++) acc[j] = 0.f;

  for (int line = 0; line < 8; line++) {
    float4 wh[4], wt[4];
#pragma unroll
    for (int i = 0; i < 4; i++) { wh[i] = whp[line * 4 + i]; wt[i] = wtp[line * 4 + i]; }
#pragma unroll
    for (int q4 = 0; q4 < 4; q4++) {
      const int qa = q4b + line * 4 + q4;
#pragma unroll
      for (int j = 0; j < NJ; j++) {
        float4 xh = ch4[j * 64 + qa];
        float4 xt = ct4[j * 64 + qa];
        acc[j] += wh[q4].x * xh.x + wh[q4].y * xh.y + wh[q4].z * xh.z + wh[q4].w * xh.w
                - (wt[q4].x * xt.x + wt[q4].y * xt.y + wt[q4].z * xt.z + wt[q4].w * xt.w);
      }
    }
  }

  const float rv = rel_embed[r * 256 + row];
#pragma unroll
  for (int j = 0; j < NJ; j++) {
    float d = acc[j] + __shfl_xor(acc[j], 1) + rv;
    float v = d * d;
    v += __shfl_down(v, 32); v += __shfl_down(v, 16);
    v += __shfl_down(v, 8);  v += __shfl_down(v, 4);
    v += __shfl_down(v, 2);  v += __shfl_down(v, 1);
    if ((tid & 63) == 0) red[j][tid >> 6] = v;
  }
  __syncthreads();
  if (tid < G) {
    float s = (red[tid][0] + red[tid][1] + red[tid][2] + red[tid][3]) * 0.5f;
    atomicAdd(&sqacc[tidx[tid]], s);
  }
  __syncthreads();
}

__global__ __launch_bounds__(256, 4) void score_grouped(
    const float* __restrict__ ctx, const float* __restrict__ trans,
    const float* __restrict__ rel_embed,
    const int* __restrict__ ph, const int* __restrict__ pt,
    const int* __restrict__ nh, const int* __restrict__ nt,
    const int* __restrict__ offs, const int* __restrict__ list,
    float* __restrict__ sqacc, int* __restrict__ done,
    float* __restrict__ out) {
  const int r = blockIdx.x >> 1, half = blockIdx.x & 1;
  int start = offs[r], end = offs[r + 1];
  __shared__ float csh[8 * 256];
  __shared__ float cst[8 * 256];
  __shared__ float red[8][4];
  __shared__ int tidx[8];
  __shared__ int lastBlock;
  __shared__ float w4[4];

  if (start < end) {
    for (int c = start; c < end; c += 8) {
      int G = min(8, end - c);
      if (G <= 4)
        score_body<4>(ctx, trans, rel_embed, ph, pt, nh, nt, list, sqacc, r, half, c, G,
                      csh, cst, red, tidx);
      else
        score_body<8>(ctx, trans, rel_embed, ph, pt, nh, nt, list, sqacc, r, half, c, G,
                      csh, cst, red, tidx);
    }
  }

  // completion counter; the last block performs the final reduction
  if (threadIdx.x == 0) {
    __threadfence();
    int old = atomicAdd(done, 1);
    lastBlock = (old == 2 * kREL - 1) ? 1 : 0;
  }
  __syncthreads();
  if (lastBlock) {
    __threadfence();
    int tid = threadIdx.x;
    float a = 0.f;
    for (int i = tid; i < 2 * kN; i += 256) {
      float s = sqrtf(sqacc[i]);
      a += (i < kN) ? s : fmaxf(0.f, 1.f - s);
    }
    for (int o = 32; o; o >>= 1) a += __shfl_down(a, o);
    if ((tid & 63) == 0) w4[tid >> 6] = a;
    __syncthreads();
    if (tid == 0) out[0] = w4[0] + w4[1] + w4[2] + w4[3];
  }
}

// ---------------- host ----------------
extern "C" void kernel_launch(void* const* d_in, const int* in_sizes, int n_in,
                              void* d_out, int out_size, void* d_ws, size_t ws_size,
                              hipStream_t stream) {
  const int*   neighbors = (const int*)d_in[0];
  const int*   pos_h = (const int*)d_in[1];
  const int*   pos_t = (const int*)d_in[2];
  const int*   pos_r = (const int*)d_in[3];
  const int*   neg_h = (const int*)d_in[4];
  const int*   neg_t = (const int*)d_in[5];
  const int*   neg_r = (const int*)d_in[6];
  const float* ent_embed = (const float*)d_in[7];
  const float* rel_embed = (const float*)d_in[8];
  const float* trans = (const float*)d_in[9];
  const float* W_ih_f = (const float*)d_in[10];
  const float* W_hh_f = (const float*)d_in[11];
  const float* W_ih_b = (const float*)d_in[12];
  const float* W_hh_b = (const float*)d_in[13];
  const float* b_f = (const float*)d_in[14];
  const float* b_b = (const float*)d_in[15];
  const float* W_lin = (const float*)d_in[16];
  const float* b_lin = (const float*)d_in[17];
  const float* gamma = (const float*)d_in[18];
  const float* beta = (const float*)d_in[19];

  char* ws = (char*)d_ws;
  size_t off = 0;
  auto alloc = [&](size_t bytes) {
    void* p = ws + off;
    off = (off + bytes + 255) & ~(size_t)255;
    return p;
  };
  u16* Wv3    = (u16*)alloc((size_t)65536 * 16);              // 1 MB
  u16* Whhr   = (u16*)alloc((size_t)2 * 1024 * kD * 2);       // 1 MB
  u16* Wlin   = (u16*)alloc((size_t)256 * kK * 2);            // 0.25 MB
  u16* ximg   = (u16*)alloc((size_t)2097152 * 16);            // 32 MB
  u16* h0     = (u16*)alloc((size_t)2 * kE * kD * 2);         // 2 MB
  u16* h1     = (u16*)alloc((size_t)2 * kE * kD * 2);         // 2 MB
  float* cbuf = (float*)alloc((size_t)2 * kE * kD * 4);       // 4 MB
  u16* gx     = (u16*)alloc((size_t)2 * kS * kE * 1024 * 2);  // 256 MB
  float* lin  = (float*)alloc((size_t)kE * 256 * 4);
  float* part = (float*)alloc((size_t)2 * 32 * 256 * 4);
  float* ctx  = (float*)alloc((size_t)kE * 256 * 4);
  float* sqacc = (float*)alloc((size_t)2 * kN * 4);
  int* offsb  = (int*)alloc((size_t)512 * 4);
  int* list   = (int*)alloc((size_t)2 * kN * 4);
  int* done   = (int*)alloc((size_t)256);
  (void)in_sizes; (void)n_in; (void)out_size; (void)ws_size;

  hipMemsetAsync(h0, 0, (size_t)2 * kE * kD * 2, stream);
  hipMemsetAsync(cbuf, 0, (size_t)2 * kE * kD * 4, stream);
  hipMemsetAsync(sqacc, 0, (size_t)2 * kN * 4, stream);
  hipMemsetAsync(done, 0, (size_t)256, stream);

  prep_gather<<<576 + 8192, 256, 0, stream>>>(W_ih_f, W_hh_f, W_ih_b, W_hh_b, W_lin,
                                              neighbors, ent_embed,
                                              Wv3, Whhr, Wlin, ximg);
  group_rel<<<1, 512, 0, stream>>>(pos_r, neg_r, offsb, list);

  xgemm<<<dim3(1024, 4, 2), 256, 0, stream>>>(ximg, Wv3, b_f, b_b, gx);

  for (int t = 0; t < kS; t++) {
    const u16* hp = (t & 1) ? h1 : h0;
    u16* hn = (t & 1) ? h0 : h1;
    lstm_step<<<256, 256, 0, stream>>>(gx, Whhr, hp, hn, cbuf, t);
  }

  lin_kernel<<<32, 256, 0, stream>>>(h0, h0 + (size_t)kE * kD, Wlin, b_lin, lin, part);
  bn_apply<<<256, 256, 0, stream>>>(lin, part, gamma, beta, ctx);
  score_grouped<<<2 * kREL, 256, 0, stream>>>(ctx, trans, rel_embed,
                                              pos_h, pos_t, neg_h, neg_t, offsb, list,
                                              sqacc, done, (float*)d_out);
}

// Round 19
// 779.089 us; speedup vs baseline: 1.0287x; 1.0287x over previous
//
#include <hip/hip_runtime.h>

// ---------------- constants ----------------
constexpr int kE   = 2048;
constexpr int kS   = 32;
constexpr int kD   = 256;
constexpr int kK   = 512;
constexpr int kREL = 500;
constexpr int kN   = 1024;

typedef unsigned short u16;
typedef __attribute__((ext_vector_type(8))) _Float16 f16x8;
typedef __attribute__((ext_vector_type(4))) float    f32x4;
typedef __attribute__((ext_vector_type(4))) unsigned short us4;

static __device__ __forceinline__ u16 f2h(float f) {
  _Float16 h = (_Float16)f;
  return __builtin_bit_cast(u16, h);
}
static __device__ __forceinline__ float h2f(u16 v) {
  _Float16 h = __builtin_bit_cast(_Float16, v);
  return (float)h;
}
static __device__ __forceinline__ float sigf(float x) { return 1.f / (1.f + __expf(-x)); }
static __device__ __forceinline__ float tanhfast(float x) {
  float e = __expf(2.f * x);
  return 1.f - 2.f / (e + 1.f);
}
static __device__ __forceinline__ void gl_lds16(const void* g, void* l) {
  __builtin_amdgcn_global_load_lds((const __attribute__((address_space(1))) unsigned int*)g,
                                   (__attribute__((address_space(3))) unsigned int*)l, 16, 0, 0);
}

// ---------------- prep+gather fused ----------------
__global__ void prep_gather(const float* __restrict__ Wih_f, const float* __restrict__ Whh_f,
                            const float* __restrict__ Wih_b, const float* __restrict__ Whh_b,
                            const float* __restrict__ Wlin_in,
                            const int* __restrict__ neighbors, const float* __restrict__ ent,
                            u16* __restrict__ Wv3, u16* __restrict__ Whhr,
                            u16* __restrict__ Wlin, u16* __restrict__ ximg) {
  if (blockIdx.x < 576) {
    int idx = blockIdx.x * 256 + threadIdx.x;
    if (idx < 65536) {                       // Wv3: 2d x 4y x 4ch x 2048 units
      int q  = idx & 2047;
      int ch = (idx >> 11) & 3;
      int y  = (idx >> 13) & 3;
      int d  = idx >> 15;
      int j  = q >> 3;
      int k8 = (q & 7) ^ (j & 7);
      int jg = y * 256 + j;
      int g = (jg >> 4) & 3, u = (jg >> 6) * 16 + (jg & 15);
      int R = g * 256 + u;
      int k = ch * 64 + k8 * 8;
      const float* src = (d ? Wih_b : Wih_f) + R * 256 + k;
      ushort oa[8];
#pragma unroll
      for (int i = 0; i < 8; i++) oa[i] = f2h(src[i]);
      *(uint4*)((char*)Wv3 + (size_t)idx * 16) = *(uint4*)oa;
    } else if (idx < 131072) {               // Whhr row-major
      int i2 = idx - 65536;
      int d = i2 >> 15;
      int j = (i2 & 32767) >> 5;
      int k = (i2 & 31) * 8;
      int g = (j >> 4) & 3, u = (j >> 6) * 16 + (j & 15);
      int R = g * 256 + u;
      const float* src = (d ? Whh_b : Whh_f) + R * 256 + k;
      ushort oa[8];
#pragma unroll
      for (int i = 0; i < 8; i++) oa[i] = f2h(src[i]);
      *(uint4*)((char*)Whhr + (size_t)i2 * 16) = *(uint4*)oa;
    } else if (idx < 131072 + 16384) {       // Wlin
      int q = (idx - 131072) * 8;
#pragma unroll
      for (int i = 0; i < 8; i++) Wlin[q + i] = f2h(Wlin_in[q + i]);
    }
  } else {
    int idx = (blockIdx.x - 576) * 256 + threadIdx.x;   // ximg units
    int q    = idx & 511;
    int ch   = (idx >> 9) & 3;
    int tile = (idx >> 11) & 31;
    int s    = idx >> 16;
    int row = q >> 3;
    int c8 = (q & 7) ^ (row & 7);
    int e = tile * 64 + row;
    int k = ch * 64 + c8 * 8;
    int nb = neighbors[e * 32 + s];
    const float* src = ent + (size_t)nb * 256 + k;
    float4 v0 = *(const float4*)src;
    float4 v1 = *(const float4*)(src + 4);
    ushort oa[8];
    oa[0] = f2h(v0.x); oa[1] = f2h(v0.y); oa[2] = f2h(v0.z); oa[3] = f2h(v0.w);
    oa[4] = f2h(v1.x); oa[5] = f2h(v1.y); oa[6] = f2h(v1.z); oa[7] = f2h(v1.w);
    *(uint4*)((char*)ximg + (size_t)idx * 16) = *(uint4*)oa;
  }
}

// ---------------- bulk xgemm: all 32 steps, LDS via gl_lds, bias in C-init ----------------
__global__ __launch_bounds__(256) void xgemm(
    const u16* __restrict__ ximg, const u16* __restrict__ Wv3,
    const float* __restrict__ b_f, const float* __restrict__ b_b,
    u16* __restrict__ gx) {
  __shared__ __align__(16) char As[8192];
  __shared__ __align__(16) char Bs[32768];
  const int tid = threadIdx.x, lane = tid & 63, w = tid >> 6;
  const int l15 = lane & 15, lq = lane >> 4;
  const int ts = blockIdx.x >> 5;
  const int etile = blockIdx.x & 31;
  const int y = blockIdx.y, dir = blockIdx.z;
  const int e0 = etile * 64;
  const int s = dir ? (31 - ts) : ts;
  const char* imgA = (const char*)ximg + (size_t)(s * 32 + etile) * 32768;
  const char* imgB = (const char*)Wv3 + (size_t)(dir * 4 + y) * 131072;
  const float* bd = dir ? b_b : b_f;
  const int u = (y * 4 + w) * 16 + l15;

  f32x4 acc[4][4];
#pragma unroll
  for (int n = 0; n < 4; n++) {
    float bv = bd[n * 256 + u];
#pragma unroll
    for (int m = 0; m < 4; m++) acc[m][n] = (f32x4){bv, bv, bv, bv};
  }

  for (int ch = 0; ch < 4; ++ch) {
#pragma unroll
    for (int i = 0; i < 2; i++)
      gl_lds16(imgA + ch * 8192 + i * 4096 + w * 1024 + lane * 16,
               As + i * 4096 + w * 1024);
#pragma unroll
    for (int i = 0; i < 8; i++)
      gl_lds16(imgB + (size_t)ch * 32768 + i * 4096 + w * 1024 + lane * 16,
               Bs + i * 4096 + w * 1024);
    __syncthreads();
#pragma unroll
    for (int ks = 0; ks < 2; ++ks) {
      const int kb = ks * 64 + lq * 16;
      f16x8 a[4], b[4];
#pragma unroll
      for (int m = 0; m < 4; m++) {
        int row = m * 16 + l15;
        a[m] = *(const f16x8*)(As + row * 128 + (kb ^ ((row & 7) << 4)));
      }
#pragma unroll
      for (int n = 0; n < 4; n++) {
        int row = w * 64 + n * 16 + l15;
        b[n] = *(const f16x8*)(Bs + row * 128 + (kb ^ ((row & 7) << 4)));
      }
#pragma unroll
      for (int m = 0; m < 4; m++)
#pragma unroll
        for (int n = 0; n < 4; n++)
          acc[m][n] = __builtin_amdgcn_mfma_f32_16x16x32_f16(a[m], b[n], acc[m][n], 0, 0, 0);
    }
    __syncthreads();
  }

  u16* out = gx + ((size_t)(dir * kS + ts) * kE) * 1024;
#pragma unroll
  for (int m = 0; m < 4; m++)
#pragma unroll
    for (int r = 0; r < 4; r++) {
      int e = e0 + m * 16 + lq * 4 + r;
      us4 o;
      o[0] = f2h(acc[m][0][r]); o[1] = f2h(acc[m][1][r]);
      o[2] = f2h(acc[m][2][r]); o[3] = f2h(acc[m][3][r]);
      __builtin_nontemporal_store(o, (us4*)(out + ((size_t)e * 256 + u) * 4));
    }
}

// ---------------- one LSTM step, h-half (K=256), 256 blocks, wave 64e x 64j ----------------
__global__ __launch_bounds__(256) void lstm_step(
    const u16* __restrict__ gx, const u16* __restrict__ Whhr,
    const u16* __restrict__ hprev, u16* __restrict__ hnext,
    float* __restrict__ cbuf, int t) {
  const int tid = threadIdx.x, lane = tid & 63, w = tid >> 6;
  const int l15 = lane & 15, lq = lane >> 4;
  const int bid = blockIdx.x;
  const int dir = bid >> 7;
  const int ut  = (bid >> 4) & 7;
  const int et  = bid & 15;
  const int wr = w >> 1, wc = w & 1;
  const int e0 = et * 128 + wr * 64;
  const int c0 = ut * 128 + wc * 64;
  const int unit = (c0 >> 6) * 16 + l15;

  const u16* Wd  = Whhr + (size_t)dir * 1024 * kD;
  const u16* hpd = hprev + (size_t)dir * kE * kD;
  u16* hnd = hnext + (size_t)dir * kE * kD;
  float* cd = cbuf + (size_t)dir * kE * kD;
  const u16* gp = gx + ((size_t)(dir * kS + t) * kE) * 1024;

  f32x4 acc[4][4];
#pragma unroll
  for (int m = 0; m < 4; m++)
#pragma unroll
    for (int r = 0; r < 4; r++) {
      us4 g = __builtin_nontemporal_load(
          (const us4*)(gp + (size_t)(e0 + m * 16 + lq * 4 + r) * 1024 + unit * 4));
#pragma unroll
      for (int n = 0; n < 4; n++) acc[m][n][r] = h2f(g[n]);
    }

  const int klane = lq * 8;
#pragma unroll
  for (int ks = 0; ks < 8; ks++) {
    const int ka = ks * 32 + klane;
    f16x8 a[4], b[4];
#pragma unroll
    for (int m = 0; m < 4; m++)
      a[m] = *(const f16x8*)(hpd + (size_t)(e0 + m * 16 + l15) * kD + ka);
#pragma unroll
    for (int n = 0; n < 4; n++)
      b[n] = *(const f16x8*)(Wd + (size_t)(c0 + n * 16 + l15) * kD + ka);
#pragma unroll
    for (int m = 0; m < 4; m++)
#pragma unroll
      for (int n = 0; n < 4; n++)
        acc[m][n] = __builtin_amdgcn_mfma_f32_16x16x32_f16(a[m], b[n], acc[m][n], 0, 0, 0);
  }

#pragma unroll
  for (int m = 0; m < 4; m++)
#pragma unroll
    for (int r = 0; r < 4; r++) {
      int row = e0 + m * 16 + lq * 4 + r;
      size_t off = (size_t)row * kD + unit;
      float gi = acc[m][0][r];
      float gf = acc[m][1][r];
      float gg = acc[m][2][r];
      float go = acc[m][3][r];
      float c_old = cd[off];
      float cn = sigf(gf) * c_old + sigf(gi) * tanhfast(gg);
      cd[off] = cn;
      hnd[off] = f2h(sigf(go) * tanhfast(cn));
    }
}

// ---------------- shared MFMA GEMM tile (used by lin) ----------------
static __device__ __forceinline__ void gemm_tile(
    const u16* __restrict__ Alo, const u16* __restrict__ Ahi,
    const u16* __restrict__ W, int e0,
    u16* As, u16* Bs, f32x4 (&acc)[4][4]) {
  const int tid = threadIdx.x;
  const int lane = tid & 63;
  const int w = tid >> 6;
#pragma unroll
  for (int m = 0; m < 4; m++)
#pragma unroll
    for (int n = 0; n < 4; n++) acc[m][n] = (f32x4){0.f, 0.f, 0.f, 0.f};

  for (int ch = 0; ch < 8; ++ch) {
    const int k0 = ch * 64;
    __syncthreads();
    const u16* Asrc = (k0 < 256) ? Alo : Ahi;
    const int kbase = (k0 < 256) ? k0 : (k0 - 256);
#pragma unroll
    for (int i = 0; i < 2; i++) {
      int idx = tid + i * 256;
      int row = idx >> 3, c8 = idx & 7;
      uint4 v = *(const uint4*)(Asrc + (size_t)(e0 + row) * 256 + kbase + c8 * 8);
      *(uint4*)((char*)As + row * 128 + ((c8 * 16) ^ ((row & 7) << 4))) = v;
    }
#pragma unroll
    for (int i = 0; i < 8; i++) {
      int idx = tid + i * 256;
      int j = idx >> 3, c8 = idx & 7;
      uint4 v = *(const uint4*)(W + (size_t)j * kK + k0 + c8 * 8);
      *(uint4*)((char*)Bs + j * 128 + ((c8 * 16) ^ ((j & 7) << 4))) = v;
    }
    __syncthreads();
#pragma unroll
    for (int ks = 0; ks < 2; ++ks) {
      const int kb = ks * 64 + (lane >> 4) * 16;
      f16x8 a[4], b[4];
#pragma unroll
      for (int m = 0; m < 4; m++) {
        int row = m * 16 + (lane & 15);
        a[m] = *(const f16x8*)((const char*)As + row * 128 + (kb ^ ((row & 7) << 4)));
      }
#pragma unroll
      for (int n = 0; n < 4; n++) {
        int row = w * 64 + n * 16 + (lane & 15);
        b[n] = *(const f16x8*)((const char*)Bs + row * 128 + (kb ^ ((row & 7) << 4)));
      }
#pragma unroll
      for (int m = 0; m < 4; m++)
#pragma unroll
        for (int n = 0; n < 4; n++)
          acc[m][n] = __builtin_amdgcn_mfma_f32_16x16x32_f16(a[m], b[n], acc[m][n], 0, 0, 0);
    }
  }
}

// ---------------- lin + fused BN partials ----------------
__global__ __launch_bounds__(256) void lin_kernel(
    const u16* __restrict__ hf, const u16* __restrict__ hb,
    const u16* __restrict__ Wl, const float* __restrict__ b_lin,
    float* __restrict__ lin, float* __restrict__ part) {
  __shared__ __align__(16) char smem[40960];
  u16* As = (u16*)smem;
  u16* Bs = (u16*)(smem + 8192);
  const int tid = threadIdx.x, lane = tid & 63, w = tid >> 6;
  const int l15 = lane & 15, lq = lane >> 4;
  const int e0 = blockIdx.x * 64;
  f32x4 acc[4][4];
  gemm_tile(hf, hb, Wl, e0, As, Bs, acc);
#pragma unroll
  for (int n = 0; n < 4; n++) {
    int col = w * 64 + n * 16 + l15;
    float bl = b_lin[col];
    float s1 = 0.f, s2 = 0.f;
#pragma unroll
    for (int m = 0; m < 4; m++)
#pragma unroll
      for (int r = 0; r < 4; r++) {
        int e = e0 + m * 16 + lq * 4 + r;
        float v = acc[m][n][r] + bl;
        lin[(size_t)e * 256 + col] = v;
        s1 += v; s2 += v * v;
      }
    s1 += __shfl_down(s1, 16); s2 += __shfl_down(s2, 16);
    s1 += __shfl_down(s1, 32); s2 += __shfl_down(s2, 32);
    if (lq == 0) {
      part[blockIdx.x * 256 + col] = s1;
      part[8192 + blockIdx.x * 256 + col] = s2;
    }
  }
}

// ---------------- BN finalize + tanh ----------------
__global__ void bn_apply(const float* __restrict__ lin, const float* __restrict__ part,
                         const float* __restrict__ gamma, const float* __restrict__ beta,
                         float* __restrict__ ctx) {
  int c = threadIdx.x;
  float s = 0.f, s2 = 0.f;
  for (int b = 0; b < 32; b++) { s += part[b * 256 + c]; s2 += part[8192 + b * 256 + c]; }
  float mu = s * (1.f / 2048.f);
  float rsig = rsqrtf(s2 * (1.f / 2048.f) - mu * mu + 1e-5f);
  float ga = gamma[c], be = beta[c];
  int e0 = blockIdx.x * 8;
  for (int e = e0; e < e0 + 8; ++e) {
    float x = lin[(size_t)e * 256 + c];
    ctx[(size_t)e * 256 + c] = tanhf(ga * (x - mu) * rsig + be);
  }
}

// ---------------- relation grouping ----------------
__global__ void group_rel(const int* __restrict__ pr, const int* __restrict__ nr,
                          int* __restrict__ offs, int* __restrict__ list) {
  __shared__ int cnt[512], sc[512], cur[512];
  int tid = threadIdx.x;
  cnt[tid] = 0;
  __syncthreads();
  for (int i = tid; i < 2 * kN; i += 512) {
    int r = (i < kN) ? pr[i] : nr[i - kN];
    atomicAdd(&cnt[r], 1);
  }
  __syncthreads();
  sc[tid] = cnt[tid];
  __syncthreads();
  for (int d = 1; d < 512; d <<= 1) {
    int v = (tid >= d) ? sc[tid - d] : 0;
    __syncthreads();
    sc[tid] += v;
    __syncthreads();
  }
  int excl = (tid == 0) ? 0 : sc[tid - 1];
  cur[tid] = excl;
  if (tid <= kREL) offs[tid] = excl;
  __syncthreads();
  for (int i = tid; i < 2 * kN; i += 512) {
    int r = (i < kN) ? pr[i] : nr[i - kN];
    int p = atomicAdd(&cur[r], 1);
    list[p] = i;
  }
}

// ---------------- scores v5: NJ<=16 single-pass, 4-float4 bursts, reg-capped ----------------
template <int NJ>
static __device__ __forceinline__ void score_body(
    const float* __restrict__ ctx, const float* __restrict__ trans,
    const float* __restrict__ rel_embed,
    const int* __restrict__ ph, const int* __restrict__ pt,
    const int* __restrict__ nh, const int* __restrict__ nt,
    const int* __restrict__ list, float* __restrict__ sqacc,
    int r, int half, int start, int G,
    float* csh, float* cst, float (*red)[4], int* tidx) {
  const int tid = threadIdx.x;
#pragma unroll
  for (int j = 0; j < NJ; j++) {
    float vh = 0.f, vt = 0.f;
    if (j < G) {
      int i = list[start + j];
      int hh = (i < kN) ? ph[i] : nh[i - kN];
      int tt = (i < kN) ? pt[i] : nt[i - kN];
      vh = ctx[(size_t)hh * 256 + tid];
      vt = ctx[(size_t)tt * 256 + tid];
      if (tid == 0) tidx[j] = i;
    }
    csh[j * 256 + tid] = vh;
    cst[j * 256 + tid] = vt;
  }
  __syncthreads();

  const int row = half * 128 + (tid >> 1);
  const int q4b = (tid & 1) * 32;
  const float4* whp = (const float4*)(trans + (size_t)r * 65536 + (size_t)row * 256) + q4b;
  const float4* wtp = (const float4*)(trans + ((size_t)r + kREL) * 65536 + (size_t)row * 256) + q4b;
  const float4* ch4 = (const float4*)csh;
  const float4* ct4 = (const float4*)cst;

  float acc[NJ];
#pragma unroll
  for (int j = 0; j < NJ; j++) acc[j] = 0.f;

  for (int line = 0; line < 8; line++) {
    float4 wh[4], wt[4];
#pragma unroll
    for (int i = 0; i < 4; i++) { wh[i] = whp[line * 4 + i]; wt[i] = wtp[line * 4 + i]; }
#pragma unroll
    for (int q4 = 0; q4 < 4; q4++) {
      const int qa = q4b + line * 4 + q4;
#pragma unroll
      for (int j = 0; j < NJ; j++) {
        float4 xh = ch4[j * 64 + qa];
        float4 xt = ct4[j * 64 + qa];
        acc[j] += wh[q4].x * xh.x + wh[q4].y * xh.y + wh[q4].z * xh.z + wh[q4].w * xh.w
                - (wt[q4].x * xt.x + wt[q4].y * xt.y + wt[q4].z * xt.z + wt[q4].w * xt.w);
      }
    }
  }

  const float rv = rel_embed[r * 256 + row];
#pragma unroll
  for (int j = 0; j < NJ; j++) {
    float d = acc[j] + __shfl_xor(acc[j], 1) + rv;
    float v = d * d;
    v += __shfl_down(v, 32); v += __shfl_down(v, 16);
    v += __shfl_down(v, 8);  v += __shfl_down(v, 4);
    v += __shfl_down(v, 2);  v += __shfl_down(v, 1);
    if ((tid & 63) == 0) red[j][tid >> 6] = v;
  }
  __syncthreads();
  if (tid < G) {
    float s = (red[tid][0] + red[tid][1] + red[tid][2] + red[tid][3]) * 0.5f;
    atomicAdd(&sqacc[tidx[tid]], s);
  }
  __syncthreads();
}

__global__ __launch_bounds__(256, 4) void score_grouped(
    const float* __restrict__ ctx, const float* __restrict__ trans,
    const float* __restrict__ rel_embed,
    const int* __restrict__ ph, const int* __restrict__ pt,
    const int* __restrict__ nh, const int* __restrict__ nt,
    const int* __restrict__ offs, const int* __restrict__ list,
    float* __restrict__ sqacc, int* __restrict__ done,
    float* __restrict__ out) {
  const int r = blockIdx.x >> 1, half = blockIdx.x & 1;
  int start = offs[r], end = offs[r + 1];
  __shared__ float csh[16 * 256];
  __shared__ float cst[16 * 256];
  __shared__ float red[16][4];
  __shared__ int tidx[16];
  __shared__ int lastBlock;
  __shared__ float w4[4];

  if (start < end) {
    for (int c = start; c < end; c += 16) {
      int G = min(16, end - c);
      if (G <= 4)
        score_body<4>(ctx, trans, rel_embed, ph, pt, nh, nt, list, sqacc, r, half, c, G,
                      csh, cst, red, tidx);
      else if (G <= 8)
        score_body<8>(ctx, trans, rel_embed, ph, pt, nh, nt, list, sqacc, r, half, c, G,
                      csh, cst, red, tidx);
      else
        score_body<16>(ctx, trans, rel_embed, ph, pt, nh, nt, list, sqacc, r, half, c, G,
                       csh, cst, red, tidx);
    }
  }

  // completion counter; the last block performs the final reduction
  if (threadIdx.x == 0) {
    __threadfence();
    int old = atomicAdd(done, 1);
    lastBlock = (old == 2 * kREL - 1) ? 1 : 0;
  }
  __syncthreads();
  if (lastBlock) {
    __threadfence();
    int tid = threadIdx.x;
    float a = 0.f;
    for (int i = tid; i < 2 * kN; i += 256) {
      float s = sqrtf(sqacc[i]);
      a += (i < kN) ? s : fmaxf(0.f, 1.f - s);
    }
    for (int o = 32; o; o >>= 1) a += __shfl_down(a, o);
    if ((tid & 63) == 0) w4[tid >> 6] = a;
    __syncthreads();
    if (tid == 0) out[0] = w4[0] + w4[1] + w4[2] + w4[3];
  }
}

// ---------------- host ----------------
extern "C" void kernel_launch(void* const* d_in, const int* in_sizes, int n_in,
                              void* d_out, int out_size, void* d_ws, size_t ws_size,
                              hipStream_t stream) {
  const int*   neighbors = (const int*)d_in[0];
  const int*   pos_h = (const int*)d_in[1];
  const int*   pos_t = (const int*)d_in[2];
  const int*   pos_r = (const int*)d_in[3];
  const int*   neg_h = (const int*)d_in[4];
  const int*   neg_t = (const int*)d_in[5];
  const int*   neg_r = (const int*)d_in[6];
  const float* ent_embed = (const float*)d_in[7];
  const float* rel_embed = (const float*)d_in[8];
  const float* trans = (const float*)d_in[9];
  const float* W_ih_f = (const float*)d_in[10];
  const float* W_hh_f = (const float*)d_in[11];
  const float* W_ih_b = (const float*)d_in[12];
  const float* W_hh_b = (const float*)d_in[13];
  const float* b_f = (const float*)d_in[14];
  const float* b_b = (const float*)d_in[15];
  const float* W_lin = (const float*)d_in[16];
  const float* b_lin = (const float*)d_in[17];
  const float* gamma = (const float*)d_in[18];
  const float* beta = (const float*)d_in[19];

  char* ws = (char*)d_ws;
  size_t off = 0;
  auto alloc = [&](size_t bytes) {
    void* p = ws + off;
    off = (off + bytes + 255) & ~(size_t)255;
    return p;
  };
  u16* Wv3    = (u16*)alloc((size_t)65536 * 16);              // 1 MB
  u16* Whhr   = (u16*)alloc((size_t)2 * 1024 * kD * 2);       // 1 MB
  u16* Wlin   = (u16*)alloc((size_t)256 * kK * 2);            // 0.25 MB
  u16* ximg   = (u16*)alloc((size_t)2097152 * 16);            // 32 MB
  u16* h0     = (u16*)alloc((size_t)2 * kE * kD * 2);         // 2 MB
  u16* h1     = (u16*)alloc((size_t)2 * kE * kD * 2);         // 2 MB
  float* cbuf = (float*)alloc((size_t)2 * kE * kD * 4);       // 4 MB
  u16* gx     = (u16*)alloc((size_t)2 * kS * kE * 1024 * 2);  // 256 MB
  float* lin  = (float*)alloc((size_t)kE * 256 * 4);
  float* part = (float*)alloc((size_t)2 * 32 * 256 * 4);
  float* ctx  = (float*)alloc((size_t)kE * 256 * 4);
  float* sqacc = (float*)alloc((size_t)2 * kN * 4);
  int* offsb  = (int*)alloc((size_t)512 * 4);
  int* list   = (int*)alloc((size_t)2 * kN * 4);
  int* done   = (int*)alloc((size_t)256);
  (void)in_sizes; (void)n_in; (void)out_size; (void)ws_size;

  hipMemsetAsync(h0, 0, (size_t)2 * kE * kD * 2, stream);
  hipMemsetAsync(cbuf, 0, (size_t)2 * kE * kD * 4, stream);
  hipMemsetAsync(sqacc, 0, (size_t)2 * kN * 4, stream);
  hipMemsetAsync(done, 0, (size_t)256, stream);

  prep_gather<<<576 + 8192, 256, 0, stream>>>(W_ih_f, W_hh_f, W_ih_b, W_hh_b, W_lin,
                                              neighbors, ent_embed,
                                              Wv3, Whhr, Wlin, ximg);
  group_rel<<<1, 512, 0, stream>>>(pos_r, neg_r, offsb, list);

  xgemm<<<dim3(1024, 4, 2), 256, 0, stream>>>(ximg, Wv3, b_f, b_b, gx);

  for (int t = 0; t < kS; t++) {
    const u16* hp = (t & 1) ? h1 : h0;
    u16* hn = (t & 1) ? h0 : h1;
    lstm_step<<<256, 256, 0, stream>>>(gx, Whhr, hp, hn, cbuf, t);
  }

  lin_kernel<<<32, 256, 0, stream>>>(h0, h0 + (size_t)kE * kD, Wlin, b_lin, lin, part);
  bn_apply<<<256, 256, 0, stream>>>(lin, part, gamma, beta, ctx);
  score_grouped<<<2 * kREL, 256, 0, stream>>>(ctx, trans, rel_embed,
                                              pos_h, pos_t, neg_h, neg_t, offsb, list,
                                              sqacc, done, (float*)d_out);
}